// Round 12
// baseline (566.160 us; speedup 1.0000x reference)
//
#include <hip/hip_runtime.h>
#include <hip/hip_bf16.h>

#define NN 100000
#define NE 1600000
#define FD 128
#define NG 100
#define GFD 16
#define GHD 32

#define NB 391     // ceil(NN/256) buckets of 256 nodes
#define BCAP 5120  // per-bucket staging capacity

typedef __attribute__((ext_vector_type(8))) _Float16 f16x8;
typedef __attribute__((ext_vector_type(4))) float f32x4;

static inline int cdiv(int a, int b) { return (a + b - 1) / b; }

// ---------------- weight conversion (all 4 layers) + init (block 256) ----------------
__global__ void k_cvt_w4(const float* __restrict__ W0, const float* __restrict__ W1,
                         const float* __restrict__ W2, const float* __restrict__ W3,
                         _Float16* __restrict__ Wf /* [4][32768] */,
                         int* __restrict__ gcur, _Float16* __restrict__ Hs) {
  if (blockIdx.x == 256) {  // init duties
    int t = threadIdx.x;
    for (int i = t; i < NB; i += 256) gcur[i] = 0;
    if (t < FD) Hs[(size_t)NN * FD + t] = (_Float16)0.f;
    return;
  }
  int tt = blockIdx.x * blockDim.x + threadIdx.x;  // 0..65535
  int layer = tt >> 14;
  int t = tt & 16383;
  const float* W = (layer == 0) ? W0 : (layer == 1) ? W1 : (layer == 2) ? W2 : W3;
  int i = t & 7;
  int l = (t >> 3) & 63;
  int nt = (t >> 9) & 7;
  int kb = (t >> 12) & 3;
  int k = kb * 32 + (l >> 4) * 8 + i;
  int n = nt * 16 + (l & 15);
  float w = W[k * FD + n];
  _Float16 hi = (_Float16)w;
  _Float16* dst = Wf + (size_t)layer * 32768;
  dst[t] = hi;
  dst[t + 16384] = (_Float16)(w - (float)hi);
}

// binA: bucket edges by dst>>8 into per-bucket staging, packed (src<<8)|(dst&255)
__global__ __launch_bounds__(256) void k_binA(const int* __restrict__ src,
                                              const int* __restrict__ dst,
                                              int* __restrict__ gcur,
                                              unsigned int* __restrict__ stag) {
  __shared__ int cnt[NB];
  __shared__ int gbase[NB];
  __shared__ int cursor[NB];
  int t = threadIdx.x;
  for (int i = t; i < NB; i += 256) cnt[i] = 0;
  __syncthreads();
  int e0 = blockIdx.x * 2048;
  int s[8], d[8], b[8];
#pragma unroll
  for (int j = 0; j < 8; j++) {
    int e = e0 + j * 256 + t;
    if (e < NE) {
      s[j] = src[e];
      d[j] = dst[e];
      b[j] = d[j] >> 8;
      atomicAdd(&cnt[b[j]], 1);
    } else {
      b[j] = -1;
    }
  }
  __syncthreads();
  for (int i = t; i < NB; i += 256) {
    int c = cnt[i];
    gbase[i] = (c > 0) ? atomicAdd(&gcur[i], c) : 0;
    cursor[i] = 0;
  }
  __syncthreads();
#pragma unroll
  for (int j = 0; j < 8; j++) {
    if (b[j] >= 0) {
      int r = atomicAdd(&cursor[b[j]], 1);
      stag[(size_t)b[j] * BCAP + gbase[b[j]] + r] =
          ((unsigned int)s[j] << 8) | (unsigned int)(d[j] & 255);
    }
  }
}

// binB: per-bucket degree histogram -> dinv + in-bucket exclusive scan of
// PADDED degree ((d+7)&~7) -> offsp, bucket total -> bsum
__global__ __launch_bounds__(256) void k_binB(const unsigned int* __restrict__ stag,
                                              const int* __restrict__ gcur,
                                              float* __restrict__ dinv,
                                              int* __restrict__ offsp,
                                              int* __restrict__ bsum) {
  __shared__ int h[256];
  __shared__ int sh[256];
  int b = blockIdx.x;
  int t = threadIdx.x;
  h[t] = 0;
  __syncthreads();
  int n = gcur[b];
  const unsigned int* p = stag + (size_t)b * BCAP;
  for (int i = t; i < n; i += 256) atomicAdd(&h[p[i] & 255], 1);
  __syncthreads();
  int node = b * 256 + t;
  int dg = h[t];
  int pd = (node < NN) ? ((dg + 7) & ~7) : 0;
  if (node < NN) dinv[node] = 1.0f / sqrtf((float)(dg + 1));
  sh[t] = pd;
  __syncthreads();
  for (int off = 1; off < 256; off <<= 1) {
    int tv = (t >= off) ? sh[t - off] : 0;
    __syncthreads();
    sh[t] += tv;
    __syncthreads();
  }
  if (node < NN) offsp[node] = sh[t] - pd;
  if (t == 255) bsum[b] = sh[255];
}

// binC: compute own bucket base (reduce bsum[0..b)), finalize offs, place
// edges, pad with sentinel NN. (scan2 folded in; bsum is read-only here)
__global__ __launch_bounds__(256) void k_binC(const unsigned int* __restrict__ stag,
                                              const int* __restrict__ gcur,
                                              const int* __restrict__ offsp,
                                              const int* __restrict__ bsum,
                                              int* __restrict__ offs,
                                              int* __restrict__ ssrc) {
  __shared__ int red[256];
  __shared__ int cur[256];
  __shared__ int nxt[256];
  int b = blockIdx.x;
  int t = threadIdx.x;
  // base = sum_{i<b} bsum[i]
  int part = 0;
  for (int i = t; i < b; i += 256) part += bsum[i];
  red[t] = part;
  __syncthreads();
  for (int s = 128; s > 0; s >>= 1) {
    if (t < s) red[t] += red[t + s];
    __syncthreads();
  }
  int base = red[0];
  int totb = bsum[b];
  __syncthreads();

  int node = b * 256 + t;
  int of = 0, ofn = 0;
  if (node < NN) {
    of = base + offsp[node];
    if (t < 255 && node + 1 < NN) {
      ofn = base + offsp[node + 1];
    } else {
      ofn = base + totb;  // first node of next bucket has in-bucket offset 0
    }
  }
  cur[t] = of;
  nxt[t] = ofn;
  __syncthreads();
  int n = gcur[b];
  const unsigned int* p = stag + (size_t)b * BCAP;
  for (int i = t; i < n; i += 256) {
    unsigned int v = p[i];
    int pos = atomicAdd(&cur[v & 255], 1);
    ssrc[pos] = (int)(v >> 8);
  }
  __syncthreads();
  if (node < NN) {
    offs[node] = of;
    if (node == NN - 1) offs[NN] = ofn;
    for (int pos = cur[t]; pos < nxt[t]; pos++) ssrc[pos] = NN;
  }
}

// ---------------- MFMA GEMM (fp16 input, dense): Hs = fp16((Xh@W)*dinv) ----------------
__global__ __launch_bounds__(256) void k_gemm_mfma(
    const _Float16* __restrict__ Xh,
    const _Float16* __restrict__ Wfrag,
    const float* __restrict__ dinv,
    _Float16* __restrict__ Hs) {
  int tid = threadIdx.x;
  int lane = tid & 63;
  int wave = tid >> 6;
  int r0 = blockIdx.x * 64 + wave * 16;
  int arow = r0 + (lane & 15);
  int kgrp = lane >> 4;

  f32x4 acc[8];
#pragma unroll
  for (int nt = 0; nt < 8; nt++) acc[nt] = (f32x4){0.f, 0.f, 0.f, 0.f};

#pragma unroll
  for (int kb = 0; kb < 4; kb++) {
    f16x8 a;
    if (arow < NN) {
      a = *(const f16x8*)(Xh + (size_t)arow * FD + kb * 32 + kgrp * 8);
    } else {
      a = (f16x8){0, 0, 0, 0, 0, 0, 0, 0};
    }
    const _Float16* wp = Wfrag + ((size_t)(kb * 8) * 64 + lane) * 8;
#pragma unroll
    for (int nt = 0; nt < 8; nt++) {
      f16x8 bhi = *(const f16x8*)(wp + (size_t)nt * 64 * 8);
      f16x8 blo = *(const f16x8*)(wp + (size_t)nt * 64 * 8 + 16384);
      acc[nt] = __builtin_amdgcn_mfma_f32_16x16x32_f16(a, bhi, acc[nt], 0, 0, 0);
      acc[nt] = __builtin_amdgcn_mfma_f32_16x16x32_f16(a, blo, acc[nt], 0, 0, 0);
    }
  }

  int ccol = lane & 15;
  int rbase = r0 + (lane >> 4) * 4;
  float dv[4];
#pragma unroll
  for (int j = 0; j < 4; j++) dv[j] = (rbase + j < NN) ? dinv[rbase + j] : 0.f;
#pragma unroll
  for (int nt = 0; nt < 8; nt++) {
#pragma unroll
    for (int j = 0; j < 4; j++) {
      int r = rbase + j;
      if (r < NN) {
        Hs[(size_t)r * FD + nt * 16 + ccol] = (_Float16)(acc[nt][j] * dv[j]);
      }
    }
  }
}

// ---------------- MFMA GEMM (fp32 input, layer 1) ----------------
__global__ __launch_bounds__(256) void k_gemm_mfma_f32(
    const float* __restrict__ X,
    const _Float16* __restrict__ Wfrag,
    const float* __restrict__ dinv,
    _Float16* __restrict__ Hs) {
  int tid = threadIdx.x;
  int lane = tid & 63;
  int wave = tid >> 6;
  int r0 = blockIdx.x * 64 + wave * 16;
  int arow = r0 + (lane & 15);
  int kgrp = lane >> 4;

  f32x4 acc[8];
#pragma unroll
  for (int nt = 0; nt < 8; nt++) acc[nt] = (f32x4){0.f, 0.f, 0.f, 0.f};

#pragma unroll
  for (int kb = 0; kb < 4; kb++) {
    f16x8 a;
    if (arow < NN) {
      const float4* xp = (const float4*)(X + (size_t)arow * FD + kb * 32 + kgrp * 8);
      float4 x0 = xp[0], x1 = xp[1];
      a = (f16x8){(_Float16)x0.x, (_Float16)x0.y, (_Float16)x0.z, (_Float16)x0.w,
                  (_Float16)x1.x, (_Float16)x1.y, (_Float16)x1.z, (_Float16)x1.w};
    } else {
      a = (f16x8){0, 0, 0, 0, 0, 0, 0, 0};
    }
    const _Float16* wp = Wfrag + ((size_t)(kb * 8) * 64 + lane) * 8;
#pragma unroll
    for (int nt = 0; nt < 8; nt++) {
      f16x8 bhi = *(const f16x8*)(wp + (size_t)nt * 64 * 8);
      f16x8 blo = *(const f16x8*)(wp + (size_t)nt * 64 * 8 + 16384);
      acc[nt] = __builtin_amdgcn_mfma_f32_16x16x32_f16(a, bhi, acc[nt], 0, 0, 0);
      acc[nt] = __builtin_amdgcn_mfma_f32_16x16x32_f16(a, blo, acc[nt], 0, 0, 0);
    }
  }

  int ccol = lane & 15;
  int rbase = r0 + (lane >> 4) * 4;
  float dv[4];
#pragma unroll
  for (int j = 0; j < 4; j++) dv[j] = (rbase + j < NN) ? dinv[rbase + j] : 0.f;
#pragma unroll
  for (int nt = 0; nt < 8; nt++) {
#pragma unroll
    for (int j = 0; j < 4; j++) {
      int r = rbase + j;
      if (r < NN) {
        Hs[(size_t)r * FD + nt * 16 + ccol] = (_Float16)(acc[nt][j] * dv[j]);
      }
    }
  }
}

// ---------------- aggregation + bias + relu (R6 best variant) ----------------
__global__ __launch_bounds__(256) void k_agg(const _Float16* __restrict__ Hs,
                                             const float* __restrict__ dinv,
                                             const int* __restrict__ offs,
                                             const int* __restrict__ ssrc,
                                             const float* __restrict__ bias,
                                             _Float16* __restrict__ Bout) {
  int wave = threadIdx.x >> 6;
  int lane = threadIdx.x & 63;
  int node = blockIdx.x * 4 + wave;  // grid exactly NN/4
  int g = lane >> 4;                 // 0..3 quadrant
  int c = lane & 15;                 // 16B chunk of the row

  int e0 = offs[node], e1 = offs[node + 1];
  int cnt = e1 - e0;  // multiple of 8
  int myidx = (lane < cnt) ? ssrc[e0 + lane] : NN;

  float acc[8];
#pragma unroll
  for (int k = 0; k < 8; k++) acc[k] = 0.f;

  for (int base = 0; base < cnt; base += 16) {
    int p = base + g * 4;
    int i0, i1, i2, i3;
    if (base < 64) {
      i0 = __builtin_amdgcn_ds_bpermute((p + 0) * 4, myidx);
      i1 = __builtin_amdgcn_ds_bpermute((p + 1) * 4, myidx);
      i2 = __builtin_amdgcn_ds_bpermute((p + 2) * 4, myidx);
      i3 = __builtin_amdgcn_ds_bpermute((p + 3) * 4, myidx);
    } else {
      i0 = (p + 0 < cnt) ? ssrc[e0 + p + 0] : NN;
      i1 = (p + 1 < cnt) ? ssrc[e0 + p + 1] : NN;
      i2 = (p + 2 < cnt) ? ssrc[e0 + p + 2] : NN;
      i3 = (p + 3 < cnt) ? ssrc[e0 + p + 3] : NN;
    }
    f16x8 v0 = *(const f16x8*)(Hs + (size_t)i0 * FD + c * 8);
    f16x8 v1 = *(const f16x8*)(Hs + (size_t)i1 * FD + c * 8);
    f16x8 v2 = *(const f16x8*)(Hs + (size_t)i2 * FD + c * 8);
    f16x8 v3 = *(const f16x8*)(Hs + (size_t)i3 * FD + c * 8);
#pragma unroll
    for (int k = 0; k < 8; k++) {
      acc[k] += ((float)v0[k] + (float)v1[k]) + ((float)v2[k] + (float)v3[k]);
    }
  }

#pragma unroll
  for (int k = 0; k < 8; k++) {
    acc[k] += __shfl_xor(acc[k], 16, 64);
    acc[k] += __shfl_xor(acc[k], 32, 64);
  }

  if (g == 0) {
    float di = dinv[node];
    f16x8 sf = *(const f16x8*)(Hs + (size_t)node * FD + c * 8);
    float4 b0 = *(const float4*)(bias + c * 8);
    float4 b1 = *(const float4*)(bias + c * 8 + 4);
    float bb[8] = {b0.x, b0.y, b0.z, b0.w, b1.x, b1.y, b1.z, b1.w};
    f16x8 o;
#pragma unroll
    for (int k = 0; k < 8; k++) {
      o[k] = (_Float16)fmaxf(fmaf(acc[k] + (float)sf[k], di, bb[k]), 0.f);
    }
    *(f16x8*)(Bout + (size_t)node * FD + c * 8) = o;
  }
}

// ---------------- fused pooling + tail MLP: one block per graph ----------------
__global__ __launch_bounds__(256) void k_pooltail(
    const _Float16* __restrict__ H, const int* __restrict__ batch,
    const float* __restrict__ gfeats,
    const float* __restrict__ W1, const float* __restrict__ b1,
    const float* __restrict__ Wg, const float* __restrict__ bg,
    const float* __restrict__ W2, const float* __restrict__ b2,
    const float* __restrict__ W3, const float* __restrict__ b3,
    const float* __restrict__ W4, const float* __restrict__ b4,
    float* __restrict__ out) {
  __shared__ float sum2[256];
  __shared__ float row[FD];
  __shared__ float y1[FD];
  __shared__ float gv[GHD];
  __shared__ float y2[FD];
  __shared__ float red[FD];
  int g = blockIdx.x;
  int t = threadIdx.x;
  int f = t & 127;
  int half = t >> 7;

  // node range of graph g (batch sorted)
  int start, end;
  {
    int lo = 0, hi = NN;
    while (lo < hi) { int m = (lo + hi) >> 1; if (batch[m] < g) lo = m + 1; else hi = m; }
    start = lo;
    lo = start; hi = NN;
    while (lo < hi) { int m = (lo + hi) >> 1; if (batch[m] < g + 1) lo = m + 1; else hi = m; }
    end = lo;
  }

  // pooled sum: 2 rows in flight (half = row parity)
  float acc = 0.f;
  for (int i = start + half; i < end; i += 2) acc += (float)H[(size_t)i * FD + f];
  sum2[t] = acc;
  __syncthreads();

  int j = t;  // active MLP lane for t < 128
  if (t < FD) row[t] = sum2[t] + sum2[t + 128];
  if (t < GHD) {
    float a = bg[t];
    for (int k = 0; k < GFD; k++) a = fmaf(gfeats[g * GFD + k], Wg[k * GHD + t], a);
    gv[t] = fmaxf(a, 0.f);
  }
  __syncthreads();

  if (j < FD) {
    float a1 = b1[j];
    for (int k = 0; k < FD; k++) a1 = fmaf(row[k], W1[k * FD + j], a1);
    y1[j] = fmaxf(a1, 0.f);
  }
  __syncthreads();

  if (j < FD) {
    float a2 = b2[j];
    for (int k = 0; k < FD; k++) a2 = fmaf(y1[k], W2[k * FD + j], a2);
    for (int k = 0; k < GHD; k++) a2 = fmaf(gv[k], W2[(FD + k) * FD + j], a2);
    y2[j] = fmaxf(a2, 0.f);
  }
  __syncthreads();

  if (j < FD) {
    float a3 = b3[j];
    for (int k = 0; k < FD; k++) a3 = fmaf(y2[k], W3[k * FD + j], a3);
    float y3 = fmaxf(a3, 0.f);
    red[j] = y3 * W4[j];
  }
  __syncthreads();
  for (int st = 64; st > 0; st >>= 1) {
    if (j < st) red[j] += red[j + st];
    __syncthreads();
  }
  if (j == 0) out[g] = red[0] + b4[0];
}

// ---------------- launcher ----------------
extern "C" void kernel_launch(void* const* d_in, const int* in_sizes, int n_in,
                              void* d_out, int out_size, void* d_ws, size_t ws_size,
                              hipStream_t stream) {
  const float* x      = (const float*)d_in[0];
  const int*   ei     = (const int*)d_in[1];
  const int*   batch  = (const int*)d_in[2];
  const float* gfeats = (const float*)d_in[3];
  const float* c1W = (const float*)d_in[5];  const float* c1b = (const float*)d_in[6];
  const float* c2W = (const float*)d_in[7];  const float* c2b = (const float*)d_in[8];
  const float* c3W = (const float*)d_in[9];  const float* c3b = (const float*)d_in[10];
  const float* c4W = (const float*)d_in[11]; const float* c4b = (const float*)d_in[12];
  const float* gW  = (const float*)d_in[13]; const float* gb  = (const float*)d_in[14];
  const float* l1W = (const float*)d_in[15]; const float* l1b = (const float*)d_in[16];
  const float* l2W = (const float*)d_in[17]; const float* l2b = (const float*)d_in[18];
  const float* l3W = (const float*)d_in[19]; const float* l3b = (const float*)d_in[20];
  const float* l4W = (const float*)d_in[21]; const float* l4b = (const float*)d_in[22];
  const int* srcp = ei;
  const int* dstp = ei + NE;
  float* out = (float*)d_out;

  char* p = (char*)d_ws;
  auto alloc = [&](size_t bytes) {
    char* r = p;
    p += (bytes + 255) & ~(size_t)255;
    return (void*)r;
  };
  _Float16* Hs  = (_Float16*)alloc((size_t)(NN + 1) * FD * 2);  // +1 sentinel zero row
  _Float16* Bb  = (_Float16*)alloc((size_t)NN * FD * 2);
  _Float16* Wf  = (_Float16*)alloc((size_t)4 * 32768 * 2);
  float* dinv = (float*)alloc((size_t)NN * 4);
  int*   offsp = (int*)alloc((size_t)NN * 4);
  int*   offs = (int*)alloc((size_t)(NN + 1) * 4);
  int*   ssrc = (int*)alloc((size_t)(NE + 8 * NN + 64) * 4);  // padded CSR + slack
  int*   bsum = (int*)alloc(512 * 4);
  unsigned int* stag = (unsigned int*)alloc((size_t)NB * BCAP * 4);  // 8 MB
  int*   gcur = (int*)alloc((size_t)NB * 4);

  // weight conversion + init (block 256)
  k_cvt_w4<<<257, 256, 0, stream>>>(c1W, c2W, c3W, c4W, Wf, gcur, Hs);

  // CSR build (bucketed, padded)
  k_binA<<<cdiv(NE, 2048), 256, 0, stream>>>(srcp, dstp, gcur, stag);
  k_binB<<<NB, 256, 0, stream>>>(stag, gcur, dinv, offsp, bsum);
  k_binC<<<NB, 256, 0, stream>>>(stag, gcur, offsp, bsum, offs, ssrc);

  // 4 GCN layers
  int gemm_grid = cdiv(NN, 64);
  const float* bs4[4] = {c1b, c2b, c3b, c4b};
  k_gemm_mfma_f32<<<gemm_grid, 256, 0, stream>>>(x, Wf, dinv, Hs);
  k_agg<<<NN / 4, 256, 0, stream>>>(Hs, dinv, offs, ssrc, bs4[0], Bb);
  for (int l = 1; l < 4; l++) {
    k_gemm_mfma<<<gemm_grid, 256, 0, stream>>>(Bb, Wf + (size_t)l * 32768, dinv, Hs);
    k_agg<<<NN / 4, 256, 0, stream>>>(Hs, dinv, offs, ssrc, bs4[l], Bb);
  }

  // fused pooling + tail
  k_pooltail<<<NG, 256, 0, stream>>>(Bb, batch, gfeats, l1W, l1b, gW, gb,
                                     l2W, l2b, l3W, l3b, l4W, l4b, out);
}

// Round 13
// 483.994 us; speedup vs baseline: 1.1698x; 1.1698x over previous
//
#include <hip/hip_runtime.h>
#include <hip/hip_bf16.h>

#define NN 100000
#define NE 1600000
#define FD 128
#define NG 100
#define GFD 16
#define GHD 32

#define NB 391     // ceil(NN/256) buckets of 256 nodes
#define BCAP 5120  // per-bucket staging capacity

typedef __attribute__((ext_vector_type(8))) _Float16 f16x8;
typedef __attribute__((ext_vector_type(4))) float f32x4;

static inline int cdiv(int a, int b) { return (a + b - 1) / b; }

// ---------------- weight conversion (all 4 layers) + init (block 256) ----------------
__global__ void k_cvt_w4(const float* __restrict__ W0, const float* __restrict__ W1,
                         const float* __restrict__ W2, const float* __restrict__ W3,
                         _Float16* __restrict__ Wf /* [4][32768] */,
                         int* __restrict__ gcur, _Float16* __restrict__ Hs) {
  if (blockIdx.x == 256) {  // init duties
    int t = threadIdx.x;
    for (int i = t; i < NB; i += 256) gcur[i] = 0;
    if (t < FD) Hs[(size_t)NN * FD + t] = (_Float16)0.f;
    return;
  }
  int tt = blockIdx.x * blockDim.x + threadIdx.x;  // 0..65535
  int layer = tt >> 14;
  int t = tt & 16383;
  const float* W = (layer == 0) ? W0 : (layer == 1) ? W1 : (layer == 2) ? W2 : W3;
  int i = t & 7;
  int l = (t >> 3) & 63;
  int nt = (t >> 9) & 7;
  int kb = (t >> 12) & 3;
  int k = kb * 32 + (l >> 4) * 8 + i;
  int n = nt * 16 + (l & 15);
  float w = W[k * FD + n];
  _Float16 hi = (_Float16)w;
  _Float16* dst = Wf + (size_t)layer * 32768;
  dst[t] = hi;
  dst[t + 16384] = (_Float16)(w - (float)hi);
}

// binA: bucket edges by dst>>8 into per-bucket staging, packed (src<<8)|(dst&255)
__global__ __launch_bounds__(256) void k_binA(const int* __restrict__ src,
                                              const int* __restrict__ dst,
                                              int* __restrict__ gcur,
                                              unsigned int* __restrict__ stag) {
  __shared__ int cnt[NB];
  __shared__ int gbase[NB];
  __shared__ int cursor[NB];
  int t = threadIdx.x;
  for (int i = t; i < NB; i += 256) cnt[i] = 0;
  __syncthreads();
  int e0 = blockIdx.x * 2048;
  int s[8], d[8], b[8];
#pragma unroll
  for (int j = 0; j < 8; j++) {
    int e = e0 + j * 256 + t;
    if (e < NE) {
      s[j] = src[e];
      d[j] = dst[e];
      b[j] = d[j] >> 8;
      atomicAdd(&cnt[b[j]], 1);
    } else {
      b[j] = -1;
    }
  }
  __syncthreads();
  for (int i = t; i < NB; i += 256) {
    int c = cnt[i];
    gbase[i] = (c > 0) ? atomicAdd(&gcur[i], c) : 0;
    cursor[i] = 0;
  }
  __syncthreads();
#pragma unroll
  for (int j = 0; j < 8; j++) {
    if (b[j] >= 0) {
      int r = atomicAdd(&cursor[b[j]], 1);
      stag[(size_t)b[j] * BCAP + gbase[b[j]] + r] =
          ((unsigned int)s[j] << 8) | (unsigned int)(d[j] & 255);
    }
  }
}

// binB: per-bucket degree histogram -> dinv + in-bucket exclusive scan of
// PADDED degree ((d+7)&~7) -> offsp, bucket total -> bsum
__global__ __launch_bounds__(256) void k_binB(const unsigned int* __restrict__ stag,
                                              const int* __restrict__ gcur,
                                              float* __restrict__ dinv,
                                              int* __restrict__ offsp,
                                              int* __restrict__ bsum) {
  __shared__ int h[256];
  __shared__ int sh[256];
  int b = blockIdx.x;
  int t = threadIdx.x;
  h[t] = 0;
  __syncthreads();
  int n = gcur[b];
  const unsigned int* p = stag + (size_t)b * BCAP;
  for (int i = t; i < n; i += 256) atomicAdd(&h[p[i] & 255], 1);
  __syncthreads();
  int node = b * 256 + t;
  int dg = h[t];
  int pd = (node < NN) ? ((dg + 7) & ~7) : 0;
  if (node < NN) dinv[node] = 1.0f / sqrtf((float)(dg + 1));
  sh[t] = pd;
  __syncthreads();
  for (int off = 1; off < 256; off <<= 1) {
    int tv = (t >= off) ? sh[t - off] : 0;
    __syncthreads();
    sh[t] += tv;
    __syncthreads();
  }
  if (node < NN) offsp[node] = sh[t] - pd;
  if (t == 255) bsum[b] = sh[255];
}

// binC: compute own bucket base (reduce bsum[0..b)), finalize offs, place
// edges, pad with sentinel NN
__global__ __launch_bounds__(256) void k_binC(const unsigned int* __restrict__ stag,
                                              const int* __restrict__ gcur,
                                              const int* __restrict__ offsp,
                                              const int* __restrict__ bsum,
                                              int* __restrict__ offs,
                                              int* __restrict__ ssrc) {
  __shared__ int red[256];
  __shared__ int cur[256];
  __shared__ int nxt[256];
  int b = blockIdx.x;
  int t = threadIdx.x;
  int part = 0;
  for (int i = t; i < b; i += 256) part += bsum[i];
  red[t] = part;
  __syncthreads();
  for (int s = 128; s > 0; s >>= 1) {
    if (t < s) red[t] += red[t + s];
    __syncthreads();
  }
  int base = red[0];
  int totb = bsum[b];
  __syncthreads();

  int node = b * 256 + t;
  int of = 0, ofn = 0;
  if (node < NN) {
    of = base + offsp[node];
    if (t < 255 && node + 1 < NN) {
      ofn = base + offsp[node + 1];
    } else {
      ofn = base + totb;
    }
  }
  cur[t] = of;
  nxt[t] = ofn;
  __syncthreads();
  int n = gcur[b];
  const unsigned int* p = stag + (size_t)b * BCAP;
  for (int i = t; i < n; i += 256) {
    unsigned int v = p[i];
    int pos = atomicAdd(&cur[v & 255], 1);
    ssrc[pos] = (int)(v >> 8);
  }
  __syncthreads();
  if (node < NN) {
    offs[node] = of;
    if (node == NN - 1) offs[NN] = ofn;
    for (int pos = cur[t]; pos < nxt[t]; pos++) ssrc[pos] = NN;
  }
}

// ---------------- MFMA GEMM (fp16 input, dense): Hs = fp16((Xh@W)*dinv) ----------------
__global__ __launch_bounds__(256) void k_gemm_mfma(
    const _Float16* __restrict__ Xh,
    const _Float16* __restrict__ Wfrag,
    const float* __restrict__ dinv,
    _Float16* __restrict__ Hs) {
  int tid = threadIdx.x;
  int lane = tid & 63;
  int wave = tid >> 6;
  int r0 = blockIdx.x * 64 + wave * 16;
  int arow = r0 + (lane & 15);
  int kgrp = lane >> 4;

  f32x4 acc[8];
#pragma unroll
  for (int nt = 0; nt < 8; nt++) acc[nt] = (f32x4){0.f, 0.f, 0.f, 0.f};

#pragma unroll
  for (int kb = 0; kb < 4; kb++) {
    f16x8 a;
    if (arow < NN) {
      a = *(const f16x8*)(Xh + (size_t)arow * FD + kb * 32 + kgrp * 8);
    } else {
      a = (f16x8){0, 0, 0, 0, 0, 0, 0, 0};
    }
    const _Float16* wp = Wfrag + ((size_t)(kb * 8) * 64 + lane) * 8;
#pragma unroll
    for (int nt = 0; nt < 8; nt++) {
      f16x8 bhi = *(const f16x8*)(wp + (size_t)nt * 64 * 8);
      f16x8 blo = *(const f16x8*)(wp + (size_t)nt * 64 * 8 + 16384);
      acc[nt] = __builtin_amdgcn_mfma_f32_16x16x32_f16(a, bhi, acc[nt], 0, 0, 0);
      acc[nt] = __builtin_amdgcn_mfma_f32_16x16x32_f16(a, blo, acc[nt], 0, 0, 0);
    }
  }

  int ccol = lane & 15;
  int rbase = r0 + (lane >> 4) * 4;
  float dv[4];
#pragma unroll
  for (int j = 0; j < 4; j++) dv[j] = (rbase + j < NN) ? dinv[rbase + j] : 0.f;
#pragma unroll
  for (int nt = 0; nt < 8; nt++) {
#pragma unroll
    for (int j = 0; j < 4; j++) {
      int r = rbase + j;
      if (r < NN) {
        Hs[(size_t)r * FD + nt * 16 + ccol] = (_Float16)(acc[nt][j] * dv[j]);
      }
    }
  }
}

// ---------------- MFMA GEMM (fp32 input, layer 1) ----------------
__global__ __launch_bounds__(256) void k_gemm_mfma_f32(
    const float* __restrict__ X,
    const _Float16* __restrict__ Wfrag,
    const float* __restrict__ dinv,
    _Float16* __restrict__ Hs) {
  int tid = threadIdx.x;
  int lane = tid & 63;
  int wave = tid >> 6;
  int r0 = blockIdx.x * 64 + wave * 16;
  int arow = r0 + (lane & 15);
  int kgrp = lane >> 4;

  f32x4 acc[8];
#pragma unroll
  for (int nt = 0; nt < 8; nt++) acc[nt] = (f32x4){0.f, 0.f, 0.f, 0.f};

#pragma unroll
  for (int kb = 0; kb < 4; kb++) {
    f16x8 a;
    if (arow < NN) {
      const float4* xp = (const float4*)(X + (size_t)arow * FD + kb * 32 + kgrp * 8);
      float4 x0 = xp[0], x1 = xp[1];
      a = (f16x8){(_Float16)x0.x, (_Float16)x0.y, (_Float16)x0.z, (_Float16)x0.w,
                  (_Float16)x1.x, (_Float16)x1.y, (_Float16)x1.z, (_Float16)x1.w};
    } else {
      a = (f16x8){0, 0, 0, 0, 0, 0, 0, 0};
    }
    const _Float16* wp = Wfrag + ((size_t)(kb * 8) * 64 + lane) * 8;
#pragma unroll
    for (int nt = 0; nt < 8; nt++) {
      f16x8 bhi = *(const f16x8*)(wp + (size_t)nt * 64 * 8);
      f16x8 blo = *(const f16x8*)(wp + (size_t)nt * 64 * 8 + 16384);
      acc[nt] = __builtin_amdgcn_mfma_f32_16x16x32_f16(a, bhi, acc[nt], 0, 0, 0);
      acc[nt] = __builtin_amdgcn_mfma_f32_16x16x32_f16(a, blo, acc[nt], 0, 0, 0);
    }
  }

  int ccol = lane & 15;
  int rbase = r0 + (lane >> 4) * 4;
  float dv[4];
#pragma unroll
  for (int j = 0; j < 4; j++) dv[j] = (rbase + j < NN) ? dinv[rbase + j] : 0.f;
#pragma unroll
  for (int nt = 0; nt < 8; nt++) {
#pragma unroll
    for (int j = 0; j < 4; j++) {
      int r = rbase + j;
      if (r < NN) {
        Hs[(size_t)r * FD + nt * 16 + ccol] = (_Float16)(acc[nt][j] * dv[j]);
      }
    }
  }
}

// ---------------- aggregation + bias + relu (R6 best variant) ----------------
__global__ __launch_bounds__(256) void k_agg(const _Float16* __restrict__ Hs,
                                             const float* __restrict__ dinv,
                                             const int* __restrict__ offs,
                                             const int* __restrict__ ssrc,
                                             const float* __restrict__ bias,
                                             _Float16* __restrict__ Bout) {
  int wave = threadIdx.x >> 6;
  int lane = threadIdx.x & 63;
  int node = blockIdx.x * 4 + wave;  // grid exactly NN/4
  int g = lane >> 4;                 // 0..3 quadrant
  int c = lane & 15;                 // 16B chunk of the row

  int e0 = offs[node], e1 = offs[node + 1];
  int cnt = e1 - e0;  // multiple of 8
  int myidx = (lane < cnt) ? ssrc[e0 + lane] : NN;

  float acc[8];
#pragma unroll
  for (int k = 0; k < 8; k++) acc[k] = 0.f;

  for (int base = 0; base < cnt; base += 16) {
    int p = base + g * 4;
    int i0, i1, i2, i3;
    if (base < 64) {
      i0 = __builtin_amdgcn_ds_bpermute((p + 0) * 4, myidx);
      i1 = __builtin_amdgcn_ds_bpermute((p + 1) * 4, myidx);
      i2 = __builtin_amdgcn_ds_bpermute((p + 2) * 4, myidx);
      i3 = __builtin_amdgcn_ds_bpermute((p + 3) * 4, myidx);
    } else {
      i0 = (p + 0 < cnt) ? ssrc[e0 + p + 0] : NN;
      i1 = (p + 1 < cnt) ? ssrc[e0 + p + 1] : NN;
      i2 = (p + 2 < cnt) ? ssrc[e0 + p + 2] : NN;
      i3 = (p + 3 < cnt) ? ssrc[e0 + p + 3] : NN;
    }
    f16x8 v0 = *(const f16x8*)(Hs + (size_t)i0 * FD + c * 8);
    f16x8 v1 = *(const f16x8*)(Hs + (size_t)i1 * FD + c * 8);
    f16x8 v2 = *(const f16x8*)(Hs + (size_t)i2 * FD + c * 8);
    f16x8 v3 = *(const f16x8*)(Hs + (size_t)i3 * FD + c * 8);
#pragma unroll
    for (int k = 0; k < 8; k++) {
      acc[k] += ((float)v0[k] + (float)v1[k]) + ((float)v2[k] + (float)v3[k]);
    }
  }

#pragma unroll
  for (int k = 0; k < 8; k++) {
    acc[k] += __shfl_xor(acc[k], 16, 64);
    acc[k] += __shfl_xor(acc[k], 32, 64);
  }

  if (g == 0) {
    float di = dinv[node];
    f16x8 sf = *(const f16x8*)(Hs + (size_t)node * FD + c * 8);
    float4 b0 = *(const float4*)(bias + c * 8);
    float4 b1 = *(const float4*)(bias + c * 8 + 4);
    float bb[8] = {b0.x, b0.y, b0.z, b0.w, b1.x, b1.y, b1.z, b1.w};
    f16x8 o;
#pragma unroll
    for (int k = 0; k < 8; k++) {
      o[k] = (_Float16)fmaxf(fmaf(acc[k] + (float)sf[k], di, bb[k]), 0.f);
    }
    *(f16x8*)(Bout + (size_t)node * FD + c * 8) = o;
  }
}

// ---------------- pooling stage 1: 8 partial chunks per graph ----------------
__global__ __launch_bounds__(128) void k_pool(const _Float16* __restrict__ H,
                                              const int* __restrict__ batch,
                                              float* __restrict__ part) {
  int g = blockIdx.x >> 3;
  int s = blockIdx.x & 7;
  int start, end;
  {
    int lo = 0, hi = NN;
    while (lo < hi) { int m = (lo + hi) >> 1; if (batch[m] < g) lo = m + 1; else hi = m; }
    start = lo;
    lo = start; hi = NN;
    while (lo < hi) { int m = (lo + hi) >> 1; if (batch[m] < g + 1) lo = m + 1; else hi = m; }
    end = lo;
  }
  int cnt = end - start;
  int chunk = (cnt + 7) >> 3;
  int a = start + s * chunk;
  int bnd = a + chunk;
  if (bnd > end) bnd = end;
  int f = threadIdx.x;
  float acc = 0.f;
  for (int i = a; i < bnd; i++) acc += (float)H[(size_t)i * FD + f];
  part[(size_t)blockIdx.x * FD + f] = acc;
}

// ---------------- tail MLP: one block per graph ----------------
__global__ __launch_bounds__(128) void k_tail(
    const float* __restrict__ part, const float* __restrict__ gfeats,
    const float* __restrict__ W1, const float* __restrict__ b1,
    const float* __restrict__ Wg, const float* __restrict__ bg,
    const float* __restrict__ W2, const float* __restrict__ b2,
    const float* __restrict__ W3, const float* __restrict__ b3,
    const float* __restrict__ W4, const float* __restrict__ b4,
    float* __restrict__ out) {
  __shared__ float row[FD];
  __shared__ float y1[FD];
  __shared__ float gv[GHD];
  __shared__ float y2[FD];
  __shared__ float red[FD];
  int g = blockIdx.x, j = threadIdx.x;

  float p = 0.f;
  for (int s = 0; s < 8; s++) p += part[(size_t)(g * 8 + s) * FD + j];
  row[j] = p;
  if (j < GHD) {
    float a = bg[j];
    for (int k = 0; k < GFD; k++) a = fmaf(gfeats[g * GFD + k], Wg[k * GHD + j], a);
    gv[j] = fmaxf(a, 0.f);
  }
  __syncthreads();

  float a1 = b1[j];
  for (int k = 0; k < FD; k++) a1 = fmaf(row[k], W1[k * FD + j], a1);
  y1[j] = fmaxf(a1, 0.f);
  __syncthreads();

  float a2 = b2[j];
  for (int k = 0; k < FD; k++) a2 = fmaf(y1[k], W2[k * FD + j], a2);
  for (int k = 0; k < GHD; k++) a2 = fmaf(gv[k], W2[(FD + k) * FD + j], a2);
  y2[j] = fmaxf(a2, 0.f);
  __syncthreads();

  float a3 = b3[j];
  for (int k = 0; k < FD; k++) a3 = fmaf(y2[k], W3[k * FD + j], a3);
  float y3 = fmaxf(a3, 0.f);

  red[j] = y3 * W4[j];
  __syncthreads();
  for (int st = 64; st > 0; st >>= 1) {
    if (j < st) red[j] += red[j + st];
    __syncthreads();
  }
  if (j == 0) out[g] = red[0] + b4[0];
}

// ---------------- launcher ----------------
extern "C" void kernel_launch(void* const* d_in, const int* in_sizes, int n_in,
                              void* d_out, int out_size, void* d_ws, size_t ws_size,
                              hipStream_t stream) {
  const float* x      = (const float*)d_in[0];
  const int*   ei     = (const int*)d_in[1];
  const int*   batch  = (const int*)d_in[2];
  const float* gfeats = (const float*)d_in[3];
  const float* c1W = (const float*)d_in[5];  const float* c1b = (const float*)d_in[6];
  const float* c2W = (const float*)d_in[7];  const float* c2b = (const float*)d_in[8];
  const float* c3W = (const float*)d_in[9];  const float* c3b = (const float*)d_in[10];
  const float* c4W = (const float*)d_in[11]; const float* c4b = (const float*)d_in[12];
  const float* gW  = (const float*)d_in[13]; const float* gb  = (const float*)d_in[14];
  const float* l1W = (const float*)d_in[15]; const float* l1b = (const float*)d_in[16];
  const float* l2W = (const float*)d_in[17]; const float* l2b = (const float*)d_in[18];
  const float* l3W = (const float*)d_in[19]; const float* l3b = (const float*)d_in[20];
  const float* l4W = (const float*)d_in[21]; const float* l4b = (const float*)d_in[22];
  const int* srcp = ei;
  const int* dstp = ei + NE;
  float* out = (float*)d_out;

  char* p = (char*)d_ws;
  auto alloc = [&](size_t bytes) {
    char* r = p;
    p += (bytes + 255) & ~(size_t)255;
    return (void*)r;
  };
  _Float16* Hs  = (_Float16*)alloc((size_t)(NN + 1) * FD * 2);  // +1 sentinel zero row
  _Float16* Bb  = (_Float16*)alloc((size_t)NN * FD * 2);
  _Float16* Wf  = (_Float16*)alloc((size_t)4 * 32768 * 2);
  float* dinv = (float*)alloc((size_t)NN * 4);
  int*   offsp = (int*)alloc((size_t)NN * 4);
  int*   offs = (int*)alloc((size_t)(NN + 1) * 4);
  int*   ssrc = (int*)alloc((size_t)(NE + 8 * NN + 64) * 4);  // padded CSR + slack
  int*   bsum = (int*)alloc(512 * 4);
  float* part = (float*)alloc((size_t)NG * 8 * FD * 4);
  unsigned int* stag = (unsigned int*)alloc((size_t)NB * BCAP * 4);  // 8 MB
  int*   gcur = (int*)alloc((size_t)NB * 4);

  // weight conversion + init (block 256)
  k_cvt_w4<<<257, 256, 0, stream>>>(c1W, c2W, c3W, c4W, Wf, gcur, Hs);

  // CSR build (bucketed, padded)
  k_binA<<<cdiv(NE, 2048), 256, 0, stream>>>(srcp, dstp, gcur, stag);
  k_binB<<<NB, 256, 0, stream>>>(stag, gcur, dinv, offsp, bsum);
  k_binC<<<NB, 256, 0, stream>>>(stag, gcur, offsp, bsum, offs, ssrc);

  // 4 GCN layers
  int gemm_grid = cdiv(NN, 64);
  const float* bs4[4] = {c1b, c2b, c3b, c4b};
  k_gemm_mfma_f32<<<gemm_grid, 256, 0, stream>>>(x, Wf, dinv, Hs);
  k_agg<<<NN / 4, 256, 0, stream>>>(Hs, dinv, offs, ssrc, bs4[0], Bb);
  for (int l = 1; l < 4; l++) {
    k_gemm_mfma<<<gemm_grid, 256, 0, stream>>>(Bb, Wf + (size_t)l * 32768, dinv, Hs);
    k_agg<<<NN / 4, 256, 0, stream>>>(Hs, dinv, offs, ssrc, bs4[l], Bb);
  }

  // pooling + tail
  k_pool<<<NG * 8, 128, 0, stream>>>(Bb, batch, part);
  k_tail<<<NG, 128, 0, stream>>>(part, gfeats, l1W, l1b, gW, gb, l2W, l2b,
                                 l3W, l3b, l4W, l4b, out);
}

// Round 14
// 452.475 us; speedup vs baseline: 1.2512x; 1.0697x over previous
//
#include <hip/hip_runtime.h>
#include <hip/hip_bf16.h>

#define NN 100000
#define NE 1600000
#define FD 128
#define NG 100
#define GFD 16
#define GHD 32

#define NB 391     // ceil(NN/256) buckets of 256 nodes
#define BCAP 5120  // per-bucket staging capacity

typedef __attribute__((ext_vector_type(8))) _Float16 f16x8;
typedef __attribute__((ext_vector_type(4))) float f32x4;

static inline int cdiv(int a, int b) { return (a + b - 1) / b; }

// ---------------- weight conversion (all 4 layers) + init (block 256) ----------------
__global__ void k_cvt_w4(const float* __restrict__ W0, const float* __restrict__ W1,
                         const float* __restrict__ W2, const float* __restrict__ W3,
                         _Float16* __restrict__ Wf /* [4][32768] */,
                         int* __restrict__ gcur, _Float16* __restrict__ Hs) {
  if (blockIdx.x == 256) {  // init duties
    int t = threadIdx.x;
    for (int i = t; i < NB; i += 256) gcur[i] = 0;
    if (t < FD) Hs[(size_t)NN * FD + t] = (_Float16)0.f;
    return;
  }
  int tt = blockIdx.x * blockDim.x + threadIdx.x;  // 0..65535
  int layer = tt >> 14;
  int t = tt & 16383;
  const float* W = (layer == 0) ? W0 : (layer == 1) ? W1 : (layer == 2) ? W2 : W3;
  int i = t & 7;
  int l = (t >> 3) & 63;
  int nt = (t >> 9) & 7;
  int kb = (t >> 12) & 3;
  int k = kb * 32 + (l >> 4) * 8 + i;
  int n = nt * 16 + (l & 15);
  float w = W[k * FD + n];
  _Float16 hi = (_Float16)w;
  _Float16* dst = Wf + (size_t)layer * 32768;
  dst[t] = hi;
  dst[t + 16384] = (_Float16)(w - (float)hi);
}

// binA: bucket edges by dst>>8 into per-bucket staging, packed (src<<8)|(dst&255)
__global__ __launch_bounds__(256) void k_binA(const int* __restrict__ src,
                                              const int* __restrict__ dst,
                                              int* __restrict__ gcur,
                                              unsigned int* __restrict__ stag) {
  __shared__ int cnt[NB];
  __shared__ int gbase[NB];
  __shared__ int cursor[NB];
  int t = threadIdx.x;
  for (int i = t; i < NB; i += 256) cnt[i] = 0;
  __syncthreads();
  int e0 = blockIdx.x * 2048;
  int s[8], d[8], b[8];
#pragma unroll
  for (int j = 0; j < 8; j++) {
    int e = e0 + j * 256 + t;
    if (e < NE) {
      s[j] = src[e];
      d[j] = dst[e];
      b[j] = d[j] >> 8;
      atomicAdd(&cnt[b[j]], 1);
    } else {
      b[j] = -1;
    }
  }
  __syncthreads();
  for (int i = t; i < NB; i += 256) {
    int c = cnt[i];
    gbase[i] = (c > 0) ? atomicAdd(&gcur[i], c) : 0;
    cursor[i] = 0;
  }
  __syncthreads();
#pragma unroll
  for (int j = 0; j < 8; j++) {
    if (b[j] >= 0) {
      int r = atomicAdd(&cursor[b[j]], 1);
      stag[(size_t)b[j] * BCAP + gbase[b[j]] + r] =
          ((unsigned int)s[j] << 8) | (unsigned int)(d[j] & 255);
    }
  }
}

// binB: per-bucket degree histogram -> dinv + in-bucket exclusive scan of
// PADDED degree ((d+7)&~7) -> offsp, bucket total -> bsum
__global__ __launch_bounds__(256) void k_binB(const unsigned int* __restrict__ stag,
                                              const int* __restrict__ gcur,
                                              float* __restrict__ dinv,
                                              int* __restrict__ offsp,
                                              int* __restrict__ bsum) {
  __shared__ int h[256];
  __shared__ int sh[256];
  int b = blockIdx.x;
  int t = threadIdx.x;
  h[t] = 0;
  __syncthreads();
  int n = gcur[b];
  const unsigned int* p = stag + (size_t)b * BCAP;
  for (int i = t; i < n; i += 256) atomicAdd(&h[p[i] & 255], 1);
  __syncthreads();
  int node = b * 256 + t;
  int dg = h[t];
  int pd = (node < NN) ? ((dg + 7) & ~7) : 0;
  if (node < NN) dinv[node] = 1.0f / sqrtf((float)(dg + 1));
  sh[t] = pd;
  __syncthreads();
  for (int off = 1; off < 256; off <<= 1) {
    int tv = (t >= off) ? sh[t - off] : 0;
    __syncthreads();
    sh[t] += tv;
    __syncthreads();
  }
  if (node < NN) offsp[node] = sh[t] - pd;
  if (t == 255) bsum[b] = sh[255];
}

// binC: compute own bucket base (reduce bsum[0..b)), finalize offs, place
// edges, pad with sentinel NN
__global__ __launch_bounds__(256) void k_binC(const unsigned int* __restrict__ stag,
                                              const int* __restrict__ gcur,
                                              const int* __restrict__ offsp,
                                              const int* __restrict__ bsum,
                                              int* __restrict__ offs,
                                              int* __restrict__ ssrc) {
  __shared__ int red[256];
  __shared__ int cur[256];
  __shared__ int nxt[256];
  int b = blockIdx.x;
  int t = threadIdx.x;
  int part = 0;
  for (int i = t; i < b; i += 256) part += bsum[i];
  red[t] = part;
  __syncthreads();
  for (int s = 128; s > 0; s >>= 1) {
    if (t < s) red[t] += red[t + s];
    __syncthreads();
  }
  int base = red[0];
  int totb = bsum[b];
  __syncthreads();

  int node = b * 256 + t;
  int of = 0, ofn = 0;
  if (node < NN) {
    of = base + offsp[node];
    if (t < 255 && node + 1 < NN) {
      ofn = base + offsp[node + 1];
    } else {
      ofn = base + totb;
    }
  }
  cur[t] = of;
  nxt[t] = ofn;
  __syncthreads();
  int n = gcur[b];
  const unsigned int* p = stag + (size_t)b * BCAP;
  for (int i = t; i < n; i += 256) {
    unsigned int v = p[i];
    int pos = atomicAdd(&cur[v & 255], 1);
    ssrc[pos] = (int)(v >> 8);
  }
  __syncthreads();
  if (node < NN) {
    offs[node] = of;
    if (node == NN - 1) offs[NN] = ofn;
    for (int pos = cur[t]; pos < nxt[t]; pos++) ssrc[pos] = NN;
  }
}

// ---------------- MFMA GEMM (fp16 input, dense): Hs = fp16((Xh@W)*dinv) ----------------
__global__ __launch_bounds__(256) void k_gemm_mfma(
    const _Float16* __restrict__ Xh,
    const _Float16* __restrict__ Wfrag,
    const float* __restrict__ dinv,
    _Float16* __restrict__ Hs) {
  int tid = threadIdx.x;
  int lane = tid & 63;
  int wave = tid >> 6;
  int r0 = blockIdx.x * 64 + wave * 16;
  int arow = r0 + (lane & 15);
  int kgrp = lane >> 4;

  f32x4 acc[8];
#pragma unroll
  for (int nt = 0; nt < 8; nt++) acc[nt] = (f32x4){0.f, 0.f, 0.f, 0.f};

#pragma unroll
  for (int kb = 0; kb < 4; kb++) {
    f16x8 a;
    if (arow < NN) {
      a = *(const f16x8*)(Xh + (size_t)arow * FD + kb * 32 + kgrp * 8);
    } else {
      a = (f16x8){0, 0, 0, 0, 0, 0, 0, 0};
    }
    const _Float16* wp = Wfrag + ((size_t)(kb * 8) * 64 + lane) * 8;
#pragma unroll
    for (int nt = 0; nt < 8; nt++) {
      f16x8 bhi = *(const f16x8*)(wp + (size_t)nt * 64 * 8);
      f16x8 blo = *(const f16x8*)(wp + (size_t)nt * 64 * 8 + 16384);
      acc[nt] = __builtin_amdgcn_mfma_f32_16x16x32_f16(a, bhi, acc[nt], 0, 0, 0);
      acc[nt] = __builtin_amdgcn_mfma_f32_16x16x32_f16(a, blo, acc[nt], 0, 0, 0);
    }
  }

  int ccol = lane & 15;
  int rbase = r0 + (lane >> 4) * 4;
  float dv[4];
#pragma unroll
  for (int j = 0; j < 4; j++) dv[j] = (rbase + j < NN) ? dinv[rbase + j] : 0.f;
#pragma unroll
  for (int nt = 0; nt < 8; nt++) {
#pragma unroll
    for (int j = 0; j < 4; j++) {
      int r = rbase + j;
      if (r < NN) {
        Hs[(size_t)r * FD + nt * 16 + ccol] = (_Float16)(acc[nt][j] * dv[j]);
      }
    }
  }
}

// ---------------- MFMA GEMM (fp32 input, layer 1) ----------------
__global__ __launch_bounds__(256) void k_gemm_mfma_f32(
    const float* __restrict__ X,
    const _Float16* __restrict__ Wfrag,
    const float* __restrict__ dinv,
    _Float16* __restrict__ Hs) {
  int tid = threadIdx.x;
  int lane = tid & 63;
  int wave = tid >> 6;
  int r0 = blockIdx.x * 64 + wave * 16;
  int arow = r0 + (lane & 15);
  int kgrp = lane >> 4;

  f32x4 acc[8];
#pragma unroll
  for (int nt = 0; nt < 8; nt++) acc[nt] = (f32x4){0.f, 0.f, 0.f, 0.f};

#pragma unroll
  for (int kb = 0; kb < 4; kb++) {
    f16x8 a;
    if (arow < NN) {
      const float4* xp = (const float4*)(X + (size_t)arow * FD + kb * 32 + kgrp * 8);
      float4 x0 = xp[0], x1 = xp[1];
      a = (f16x8){(_Float16)x0.x, (_Float16)x0.y, (_Float16)x0.z, (_Float16)x0.w,
                  (_Float16)x1.x, (_Float16)x1.y, (_Float16)x1.z, (_Float16)x1.w};
    } else {
      a = (f16x8){0, 0, 0, 0, 0, 0, 0, 0};
    }
    const _Float16* wp = Wfrag + ((size_t)(kb * 8) * 64 + lane) * 8;
#pragma unroll
    for (int nt = 0; nt < 8; nt++) {
      f16x8 bhi = *(const f16x8*)(wp + (size_t)nt * 64 * 8);
      f16x8 blo = *(const f16x8*)(wp + (size_t)nt * 64 * 8 + 16384);
      acc[nt] = __builtin_amdgcn_mfma_f32_16x16x32_f16(a, bhi, acc[nt], 0, 0, 0);
      acc[nt] = __builtin_amdgcn_mfma_f32_16x16x32_f16(a, blo, acc[nt], 0, 0, 0);
    }
  }

  int ccol = lane & 15;
  int rbase = r0 + (lane >> 4) * 4;
  float dv[4];
#pragma unroll
  for (int j = 0; j < 4; j++) dv[j] = (rbase + j < NN) ? dinv[rbase + j] : 0.f;
#pragma unroll
  for (int nt = 0; nt < 8; nt++) {
#pragma unroll
    for (int j = 0; j < 4; j++) {
      int r = rbase + j;
      if (r < NN) {
        Hs[(size_t)r * FD + nt * 16 + ccol] = (_Float16)(acc[nt][j] * dv[j]);
      }
    }
  }
}

// ---------------- aggregation + bias + relu (R6 best variant) ----------------
__global__ __launch_bounds__(256) void k_agg(const _Float16* __restrict__ Hs,
                                             const float* __restrict__ dinv,
                                             const int* __restrict__ offs,
                                             const int* __restrict__ ssrc,
                                             const float* __restrict__ bias,
                                             _Float16* __restrict__ Bout) {
  int wave = threadIdx.x >> 6;
  int lane = threadIdx.x & 63;
  int node = blockIdx.x * 4 + wave;  // grid exactly NN/4
  int g = lane >> 4;                 // 0..3 quadrant
  int c = lane & 15;                 // 16B chunk of the row

  int e0 = offs[node], e1 = offs[node + 1];
  int cnt = e1 - e0;  // multiple of 8
  int myidx = (lane < cnt) ? ssrc[e0 + lane] : NN;

  float acc[8];
#pragma unroll
  for (int k = 0; k < 8; k++) acc[k] = 0.f;

  for (int base = 0; base < cnt; base += 16) {
    int p = base + g * 4;
    int i0, i1, i2, i3;
    if (base < 64) {
      i0 = __builtin_amdgcn_ds_bpermute((p + 0) * 4, myidx);
      i1 = __builtin_amdgcn_ds_bpermute((p + 1) * 4, myidx);
      i2 = __builtin_amdgcn_ds_bpermute((p + 2) * 4, myidx);
      i3 = __builtin_amdgcn_ds_bpermute((p + 3) * 4, myidx);
    } else {
      i0 = (p + 0 < cnt) ? ssrc[e0 + p + 0] : NN;
      i1 = (p + 1 < cnt) ? ssrc[e0 + p + 1] : NN;
      i2 = (p + 2 < cnt) ? ssrc[e0 + p + 2] : NN;
      i3 = (p + 3 < cnt) ? ssrc[e0 + p + 3] : NN;
    }
    f16x8 v0 = *(const f16x8*)(Hs + (size_t)i0 * FD + c * 8);
    f16x8 v1 = *(const f16x8*)(Hs + (size_t)i1 * FD + c * 8);
    f16x8 v2 = *(const f16x8*)(Hs + (size_t)i2 * FD + c * 8);
    f16x8 v3 = *(const f16x8*)(Hs + (size_t)i3 * FD + c * 8);
#pragma unroll
    for (int k = 0; k < 8; k++) {
      acc[k] += ((float)v0[k] + (float)v1[k]) + ((float)v2[k] + (float)v3[k]);
    }
  }

#pragma unroll
  for (int k = 0; k < 8; k++) {
    acc[k] += __shfl_xor(acc[k], 16, 64);
    acc[k] += __shfl_xor(acc[k], 32, 64);
  }

  if (g == 0) {
    float di = dinv[node];
    f16x8 sf = *(const f16x8*)(Hs + (size_t)node * FD + c * 8);
    float4 b0 = *(const float4*)(bias + c * 8);
    float4 b1 = *(const float4*)(bias + c * 8 + 4);
    float bb[8] = {b0.x, b0.y, b0.z, b0.w, b1.x, b1.y, b1.z, b1.w};
    f16x8 o;
#pragma unroll
    for (int k = 0; k < 8; k++) {
      o[k] = (_Float16)fmaxf(fmaf(acc[k] + (float)sf[k], di, bb[k]), 0.f);
    }
    *(f16x8*)(Bout + (size_t)node * FD + c * 8) = o;
  }
}

// ---------------- pooling stage 1: vectorized f16x8 loads ----------------
// 8 chunks/graph. Lane = (sub = t>>4 row-parity, cl = t&15 16B chunk); each
// iteration covers 8 rows x full 256B. fp32 acc in regs, LDS combine.
__global__ __launch_bounds__(128) void k_pool(const _Float16* __restrict__ H,
                                              const int* __restrict__ batch,
                                              float* __restrict__ part) {
  __shared__ float lds[8][FD];
  int g = blockIdx.x >> 3;
  int s = blockIdx.x & 7;
  int start, end;
  {
    int lo = 0, hi = NN;
    while (lo < hi) { int m = (lo + hi) >> 1; if (batch[m] < g) lo = m + 1; else hi = m; }
    start = lo;
    lo = start; hi = NN;
    while (lo < hi) { int m = (lo + hi) >> 1; if (batch[m] < g + 1) lo = m + 1; else hi = m; }
    end = lo;
  }
  int cnt = end - start;
  int chunk = (cnt + 7) >> 3;
  int a = start + s * chunk;
  int bnd = a + chunk;
  if (bnd > end) bnd = end;

  int sub = threadIdx.x >> 4;  // 0..7
  int cl = threadIdx.x & 15;   // 16B chunk of row
  float acc[8];
#pragma unroll
  for (int k = 0; k < 8; k++) acc[k] = 0.f;
  for (int i = a + sub; i < bnd; i += 8) {
    f16x8 v = *(const f16x8*)(H + (size_t)i * FD + cl * 8);
#pragma unroll
    for (int k = 0; k < 8; k++) acc[k] += (float)v[k];
  }
#pragma unroll
  for (int k = 0; k < 8; k++) lds[sub][cl * 8 + k] = acc[k];
  __syncthreads();

  int f = threadIdx.x;  // 0..127 feature
  float s0 = 0.f;
#pragma unroll
  for (int r = 0; r < 8; r++) s0 += lds[r][f];
  part[(size_t)blockIdx.x * FD + f] = s0;
}

// ---------------- tail MLP: one block per graph ----------------
__global__ __launch_bounds__(128) void k_tail(
    const float* __restrict__ part, const float* __restrict__ gfeats,
    const float* __restrict__ W1, const float* __restrict__ b1,
    const float* __restrict__ Wg, const float* __restrict__ bg,
    const float* __restrict__ W2, const float* __restrict__ b2,
    const float* __restrict__ W3, const float* __restrict__ b3,
    const float* __restrict__ W4, const float* __restrict__ b4,
    float* __restrict__ out) {
  __shared__ float row[FD];
  __shared__ float y1[FD];
  __shared__ float gv[GHD];
  __shared__ float y2[FD];
  __shared__ float red[FD];
  int g = blockIdx.x, j = threadIdx.x;

  float p = 0.f;
  for (int s = 0; s < 8; s++) p += part[(size_t)(g * 8 + s) * FD + j];
  row[j] = p;
  if (j < GHD) {
    float a = bg[j];
    for (int k = 0; k < GFD; k++) a = fmaf(gfeats[g * GFD + k], Wg[k * GHD + j], a);
    gv[j] = fmaxf(a, 0.f);
  }
  __syncthreads();

  float a1 = b1[j];
  for (int k = 0; k < FD; k++) a1 = fmaf(row[k], W1[k * FD + j], a1);
  y1[j] = fmaxf(a1, 0.f);
  __syncthreads();

  float a2 = b2[j];
  for (int k = 0; k < FD; k++) a2 = fmaf(y1[k], W2[k * FD + j], a2);
  for (int k = 0; k < GHD; k++) a2 = fmaf(gv[k], W2[(FD + k) * FD + j], a2);
  y2[j] = fmaxf(a2, 0.f);
  __syncthreads();

  float a3 = b3[j];
  for (int k = 0; k < FD; k++) a3 = fmaf(y2[k], W3[k * FD + j], a3);
  float y3 = fmaxf(a3, 0.f);

  red[j] = y3 * W4[j];
  __syncthreads();
  for (int st = 64; st > 0; st >>= 1) {
    if (j < st) red[j] += red[j + st];
    __syncthreads();
  }
  if (j == 0) out[g] = red[0] + b4[0];
}

// ---------------- launcher ----------------
extern "C" void kernel_launch(void* const* d_in, const int* in_sizes, int n_in,
                              void* d_out, int out_size, void* d_ws, size_t ws_size,
                              hipStream_t stream) {
  const float* x      = (const float*)d_in[0];
  const int*   ei     = (const int*)d_in[1];
  const int*   batch  = (const int*)d_in[2];
  const float* gfeats = (const float*)d_in[3];
  const float* c1W = (const float*)d_in[5];  const float* c1b = (const float*)d_in[6];
  const float* c2W = (const float*)d_in[7];  const float* c2b = (const float*)d_in[8];
  const float* c3W = (const float*)d_in[9];  const float* c3b = (const float*)d_in[10];
  const float* c4W = (const float*)d_in[11]; const float* c4b = (const float*)d_in[12];
  const float* gW  = (const float*)d_in[13]; const float* gb  = (const float*)d_in[14];
  const float* l1W = (const float*)d_in[15]; const float* l1b = (const float*)d_in[16];
  const float* l2W = (const float*)d_in[17]; const float* l2b = (const float*)d_in[18];
  const float* l3W = (const float*)d_in[19]; const float* l3b = (const float*)d_in[20];
  const float* l4W = (const float*)d_in[21]; const float* l4b = (const float*)d_in[22];
  const int* srcp = ei;
  const int* dstp = ei + NE;
  float* out = (float*)d_out;

  char* p = (char*)d_ws;
  auto alloc = [&](size_t bytes) {
    char* r = p;
    p += (bytes + 255) & ~(size_t)255;
    return (void*)r;
  };
  _Float16* Hs  = (_Float16*)alloc((size_t)(NN + 1) * FD * 2);  // +1 sentinel zero row
  _Float16* Bb  = (_Float16*)alloc((size_t)NN * FD * 2);
  _Float16* Wf  = (_Float16*)alloc((size_t)4 * 32768 * 2);
  float* dinv = (float*)alloc((size_t)NN * 4);
  int*   offsp = (int*)alloc((size_t)NN * 4);
  int*   offs = (int*)alloc((size_t)(NN + 1) * 4);
  int*   ssrc = (int*)alloc((size_t)(NE + 8 * NN + 64) * 4);  // padded CSR + slack
  int*   bsum = (int*)alloc(512 * 4);
  float* part = (float*)alloc((size_t)NG * 8 * FD * 4);
  unsigned int* stag = (unsigned int*)alloc((size_t)NB * BCAP * 4);  // 8 MB
  int*   gcur = (int*)alloc((size_t)NB * 4);

  // weight conversion + init (block 256)
  k_cvt_w4<<<257, 256, 0, stream>>>(c1W, c2W, c3W, c4W, Wf, gcur, Hs);

  // CSR build (bucketed, padded)
  k_binA<<<cdiv(NE, 2048), 256, 0, stream>>>(srcp, dstp, gcur, stag);
  k_binB<<<NB, 256, 0, stream>>>(stag, gcur, dinv, offsp, bsum);
  k_binC<<<NB, 256, 0, stream>>>(stag, gcur, offsp, bsum, offs, ssrc);

  // 4 GCN layers
  int gemm_grid = cdiv(NN, 64);
  const float* bs4[4] = {c1b, c2b, c3b, c4b};
  k_gemm_mfma_f32<<<gemm_grid, 256, 0, stream>>>(x, Wf, dinv, Hs);
  k_agg<<<NN / 4, 256, 0, stream>>>(Hs, dinv, offs, ssrc, bs4[0], Bb);
  for (int l = 1; l < 4; l++) {
    k_gemm_mfma<<<gemm_grid, 256, 0, stream>>>(Bb, Wf + (size_t)l * 32768, dinv, Hs);
    k_agg<<<NN / 4, 256, 0, stream>>>(Hs, dinv, offs, ssrc, bs4[l], Bb);
  }

  // pooling + tail
  k_pool<<<NG * 8, 128, 0, stream>>>(Bb, batch, part);
  k_tail<<<NG, 128, 0, stream>>>(part, gfeats, l1W, l1b, gW, gb, l2W, l2b,
                                 l3W, l3b, l4W, l4b, out);
}